// Round 11
// baseline (205.741 us; speedup 1.0000x reference)
//
#include <hip/hip_runtime.h>

// Attention forward, (B,H,D,N)=(4,16,64,2048), fp32 in/out. Flash-style.
// Round 15: R14 base (86.9us best) + barrier-every-2-tiles. R13's idea with
// its failure modes removed: MACROS not lambdas (pure textual inlining, no
// array-param decay -> no scratch), role-split staging (2-tile prefetch =
// only 16 VGPR), static period-4 buffer pointers unrolled x2. Phase =
// {load 2 tiles to regs, compute tile a, compute tile b, write both, ONE
// barrier}: tile b's QK/ds-reads independent of tile a's PV -> 2x scheduler
// window; barrier drains 31 -> 16. Geometry = R14: 512-q tile, 16 waves x
// 32 q-cols, 1024 thr, grid 256 (1 block/CU), LDS 73728 B (4 x 18432).

#define DDIM 64
#define NSEQ 2048
#define STR  72               // f16 elems per LDS row (64 + 8 pad), 144 B
#define BUFB (128 * STR * 2)  // one K+V buffer: 64 K-rows + 64 V-rows = 18432 B

typedef _Float16 half8   __attribute__((ext_vector_type(8)));
typedef _Float16 half4v  __attribute__((ext_vector_type(4)));
typedef _Float16 half2v  __attribute__((ext_vector_type(2)));
typedef float    float4v __attribute__((ext_vector_type(4)));

// role-split raw prefetch of tile starting at column (J1)
#define LOADT(J1, RA, RB)                                                   \
  do {                                                                      \
    if (isK) { RA = *(const float4v*)(kp + (J1));                           \
               RB = *(const float4v*)(kp + NSEQ + (J1)); }                  \
    else     { RA = *(const float4v*)(vpA + (J1));                          \
               RB = *(const float4v*)(vpA + (J1) + 16); }                   \
  } while (0)

// role-split convert+write of raw regs into buffer BUF
#define WTILE(BUF, RA, RB)                                                  \
  do {                                                                      \
    _Float16* Ktw_ = (_Float16*)(BUF);                                      \
    if (isK) {                                                              \
      _Float16* base_ = Ktw_ + (iq * 4) * STR + 2 * dp;                     \
      _Pragma("unroll")                                                     \
      for (int s_ = 0; s_ < 4; ++s_) {                                      \
        half2v hh_ = {(_Float16)RA[s_], (_Float16)RB[s_]};                  \
        *(half2v*)(base_ + s_ * STR) = hh_;                                 \
      }                                                                     \
    } else {                                                                \
      half8 hv_ = {(_Float16)RA[0], (_Float16)RA[1], (_Float16)RA[2],       \
                   (_Float16)RA[3], (_Float16)RB[0], (_Float16)RB[1],       \
                   (_Float16)RB[2], (_Float16)RB[3]};                       \
      *(half8*)(Ktw_ + 64 * STR + vd * STR + sj * 8) = hv_;                 \
    }                                                                       \
  } while (0)

// full per-tile compute (QK -> exp2 -> pack -> lac + PV) from buffer KBUF
#define CTILE(KBUF)                                                         \
  do {                                                                      \
    const _Float16* Kt_ = (const _Float16*)(KBUF);                          \
    const _Float16* Vt_ = Kt_ + 64 * STR;                                   \
    half4v p_[2][4];                                                        \
    _Pragma("unroll")                                                       \
    for (int jt = 0; jt < 4; ++jt) {                                        \
      half8 kfa = *(const half8*)(Kt_ + (jt * 16 + n16) * STR + quad * 8);  \
      half8 kfb = *(const half8*)(Kt_ + (jt * 16 + n16) * STR + 32 + quad * 8); \
      _Pragma("unroll")                                                     \
      for (int ig = 0; ig < 2; ++ig) {                                      \
        float4v sa = {0.f, 0.f, 0.f, 0.f};                                  \
        sa = __builtin_amdgcn_mfma_f32_16x16x32_f16(kfa, bq[ig][0], sa, 0, 0, 0); \
        sa = __builtin_amdgcn_mfma_f32_16x16x32_f16(kfb, bq[ig][1], sa, 0, 0, 0); \
        p_[ig][jt] = (half4v){(_Float16)__builtin_amdgcn_exp2f(sa[0]),      \
                              (_Float16)__builtin_amdgcn_exp2f(sa[1]),      \
                              (_Float16)__builtin_amdgcn_exp2f(sa[2]),      \
                              (_Float16)__builtin_amdgcn_exp2f(sa[3])};     \
      }                                                                     \
    }                                                                       \
    half8 pg_[2][2];                                                        \
    _Pragma("unroll")                                                       \
    for (int ig = 0; ig < 2; ++ig) {                                        \
      pg_[ig][0] = __builtin_shufflevector(p_[ig][0], p_[ig][1], 0, 1, 2, 3, 4, 5, 6, 7); \
      pg_[ig][1] = __builtin_shufflevector(p_[ig][2], p_[ig][3], 0, 1, 2, 3, 4, 5, 6, 7); \
    }                                                                       \
    __builtin_amdgcn_s_setprio(1);                                          \
    _Pragma("unroll")                                                       \
    for (int ig = 0; ig < 2; ++ig) {                                        \
      lac[ig] = __builtin_amdgcn_mfma_f32_16x16x32_f16(ones, pg_[ig][0], lac[ig], 0, 0, 0); \
      lac[ig] = __builtin_amdgcn_mfma_f32_16x16x32_f16(ones, pg_[ig][1], lac[ig], 0, 0, 0); \
    }                                                                       \
    _Pragma("unroll")                                                       \
    for (int dt = 0; dt < 4; ++dt) {                                        \
      _Pragma("unroll")                                                     \
      for (int g = 0; g < 2; ++g) {                                         \
        half8 vaf = *(const half8*)(Vt_ + (dt * 16 + n16) * STR + (g * 4 + quad) * 8); \
        _Pragma("unroll")                                                   \
        for (int ig = 0; ig < 2; ++ig) {                                    \
          o[ig][dt] = __builtin_amdgcn_mfma_f32_16x16x32_f16(vaf, pg_[ig][g], o[ig][dt], 0, 0, 0); \
        }                                                                   \
      }                                                                     \
    }                                                                       \
    __builtin_amdgcn_s_setprio(0);                                          \
  } while (0)

__global__ __launch_bounds__(1024, 4) void attn_fwd(
    const float* __restrict__ qg, const float* __restrict__ kg,
    const float* __restrict__ vg, float* __restrict__ og) {
  // 73728 B: Q prestage uses all of it (512 rows x 144 B); the K-loop uses
  // four 18432 B K/V buffers, tile t in buffer (t+1)&3.
  __shared__ __align__(16) char smem[4 * BUFB];

  const int t    = threadIdx.x;
  const int lane = t & 63;
  const int w    = t >> 6;      // wave 0..15 -> query cols w*32 .. w*32+31
  const int n16  = lane & 15;
  const int quad = lane >> 4;

  // XCD swizzle: 32 blocks/XCD; same-XCD slots walk 4 q-tiles of 8 heads.
  const int bid  = blockIdx.x;
  const int head = ((bid & 7) << 3) | (bid >> 5);
  const int tile = (bid >> 3) & 3;
  const int i0   = tile * 512;

  const float* qh = qg + (size_t)head * DDIM * NSEQ;
  const float* kh = kg + (size_t)head * DDIM * NSEQ;
  const float* vh = vg + (size_t)head * DDIM * NSEQ;

  // staging role split: waves 0..7 (t<512) stage K, waves 8..15 stage V
  const int  u   = t & 511;
  const bool isK = (t < 512);
  const int  dp  = u & 31;      // K: d-pair (transpose staging)
  const int  iq  = u >> 5;      // K: j-chunk of 4, 0..15
  const int  vd  = u >> 3;      // V: row (d), 0..63
  const int  sj  = u & 7;       // V: k-slot 0..7
  const int  vg_ = sj >> 2;     // g of slot
  const int  vq  = sj & 3;      // quad of slot

  const float* kp  = kh + (2 * dp) * NSEQ + iq * 4;
  const float* vpA = vh + vd * NSEQ + vg_ * 32 + vq * 4;  // first 4 cols of slot

  char* const Bb0 = smem;
  char* const Bb1 = smem + BUFB;
  char* const Bb2 = smem + 2 * BUFB;
  char* const Bb3 = smem + 3 * BUFB;

  // issue tiles 0,1 global loads first: HBM latency hides under Q prestage
  float4v ra, rb, rc, rd;
  LOADT(0, ra, rb);
  LOADT(64, rc, rd);

  // ---- pre-stage Q: q[d][i0+..] -> Qt[i][d] (512 rows, all 4 buffers) ----
  {
    _Float16* Qt = (_Float16*)smem;
    const float mul = 0.125f * 1.44269504088896340736f;
    const int dpq = t & 31;     // d-pair
    const int ic  = t >> 5;     // i-chunk of 4, 0..31
#pragma unroll
    for (int h = 0; h < 4; ++h) {
      const float* r0 = qh + (2 * dpq) * NSEQ + i0 + h * 128 + ic * 4;
      float4v a = *(const float4v*)(r0);
      float4v b = *(const float4v*)(r0 + NSEQ);
      _Float16* base = Qt + (h * 128 + ic * 4) * STR + 2 * dpq;
#pragma unroll
      for (int s = 0; s < 4; ++s) {
        half2v hh = {(_Float16)(a[s] * mul), (_Float16)(b[s] * mul)};
        *(half2v*)(base + s * STR) = hh;
      }
    }
  }
  __syncthreads();

  // Q B-fragments — live all kernel (2 x 16-col groups per wave)
  const _Float16* Qt = (const _Float16*)smem;
  half8 bq[2][2];
#pragma unroll
  for (int ig = 0; ig < 2; ++ig) {
    bq[ig][0] = *(const half8*)(Qt + (w * 32 + ig * 16 + n16) * STR + quad * 8);
    bq[ig][1] = *(const half8*)(Qt + (w * 32 + ig * 16 + n16) * STR + 32 + quad * 8);
  }
  __syncthreads();  // all Q reads drained before tiles 0,1 overwrite b1,b2

  // stage tiles 0 -> b1, 1 -> b2
  WTILE(Bb1, ra, rb);
  WTILE(Bb2, rc, rd);
  __syncthreads();

  const half8 ones = {1.0f16, 1.0f16, 1.0f16, 1.0f16,
                      1.0f16, 1.0f16, 1.0f16, 1.0f16};

  float4v o[2][4];          // [ig][dt]: O^T[d = dt*16+quad*4+r][i-group ig]
  float4v lac[2];           // row-sum accumulators (all regs equal l[n16])
#pragma unroll
  for (int ig = 0; ig < 2; ++ig) {
#pragma unroll
    for (int dt = 0; dt < 4; ++dt) o[ig][dt] = (float4v){0.f, 0.f, 0.f, 0.f};
    lac[ig] = (float4v){0.f, 0.f, 0.f, 0.f};
  }

  // ---- main loop: 8 super-iters x 4 tiles; tile t lives in buf (t+1)&3 ----
#pragma unroll 1
  for (int m = 0; m < 8; ++m) {
    const int bt = m * 4;
    // Phase A: compute tiles bt (b1), bt+1 (b2); stage bt+2 -> b3, bt+3 -> b0
    LOADT((bt + 2) * 64, ra, rb);
    LOADT((bt + 3) * 64, rc, rd);
    CTILE(Bb1);
    CTILE(Bb2);
    WTILE(Bb3, ra, rb);
    WTILE(Bb0, rc, rd);
    __syncthreads();

    // Phase B: compute tiles bt+2 (b3), bt+3 (b0); stage bt+4 -> b1, bt+5 -> b2
    if (m < 7) {
      LOADT((bt + 4) * 64, ra, rb);
      LOADT((bt + 5) * 64, rc, rd);
    }
    CTILE(Bb3);
    CTILE(Bb0);
    if (m < 7) {
      WTILE(Bb1, ra, rb);
      WTILE(Bb2, rc, rd);
      __syncthreads();
    }
  }

  // ---- epilogue: all regs of lac hold l[i]; direct O^T stores ----
#pragma unroll
  for (int ig = 0; ig < 2; ++ig) {
    const float inv = 1.0f / lac[ig][0];
    float* ob = og + (size_t)head * DDIM * NSEQ + i0 + w * 32 + ig * 16 + n16;
#pragma unroll
    for (int dt = 0; dt < 4; ++dt) {
#pragma unroll
      for (int r = 0; r < 4; ++r) {
        ob[(size_t)(dt * 16 + quad * 4 + r) * NSEQ] = o[ig][dt][r] * inv;
      }
    }
  }
}

extern "C" void kernel_launch(void* const* d_in, const int* in_sizes, int n_in,
                              void* d_out, int out_size, void* d_ws, size_t ws_size,
                              hipStream_t stream) {
  (void)in_sizes; (void)n_in; (void)d_ws; (void)ws_size; (void)out_size;
  const float* q = (const float*)d_in[0];
  const float* k = (const float*)d_in[1];
  const float* v = (const float*)d_in[2];
  attn_fwd<<<dim3(256), dim3(1024), 0, stream>>>(q, k, v, (float*)d_out);
}

// Round 12
// 186.393 us; speedup vs baseline: 1.1038x; 1.1038x over previous
//
#include <hip/hip_runtime.h>

// Attention forward, (B,H,D,N)=(4,16,64,2048), fp32 in/out. Flash-style.
// Round 16: R14 base (86.9us best) with ONE change: staging (vmcnt wait +
// f32->f16 cvt + ds_writes) moved from after the PV cluster to before it.
// The cvt VALU fills the matrix-idle gap after pack; ds_writes drain under
// the 20 lac+PV MFMAs; the barrier arrives nearly drained (removes the
// per-wave serial staging tail in front of every barrier). Write buffer
// (kt&1) is disjoint from this tile's read buffer ((kt+1)&1), and the
// previous barrier fenced tile kt-1's reads of kt&1 -> safe. Everything
// else byte-identical to R14: 512-q tile, 16 waves x 32 q-cols, 1024 thr,
// grid 256 (1 block/CU), role-split staging, STR=72 layout.

#define DDIM 64
#define NSEQ 2048
#define STR  72               // f16 elems per LDS row (64 + 8 pad), 144 B
#define BUFB (128 * STR * 2)  // one K+V buffer: 64 K-rows + 64 V-rows = 18432 B

typedef _Float16 half8   __attribute__((ext_vector_type(8)));
typedef _Float16 half4v  __attribute__((ext_vector_type(4)));
typedef _Float16 half2v  __attribute__((ext_vector_type(2)));
typedef float    float4v __attribute__((ext_vector_type(4)));

__global__ __launch_bounds__(1024, 4) void attn_fwd(
    const float* __restrict__ qg, const float* __restrict__ kg,
    const float* __restrict__ vg, float* __restrict__ og) {
  // 73728 B: Q prestage uses all of it (512 rows x 144 B); the K-loop uses
  // the first two 18432 B K/V buffers (tile kt lives in buffer (kt+1)&1).
  __shared__ __align__(16) char smem[4 * BUFB];

  const int t    = threadIdx.x;
  const int lane = t & 63;
  const int w    = t >> 6;      // wave 0..15 -> query cols w*32 .. w*32+31
  const int n16  = lane & 15;
  const int quad = lane >> 4;

  // XCD swizzle: 32 blocks/XCD; same-XCD slots walk 4 q-tiles of 8 heads.
  const int bid  = blockIdx.x;
  const int head = ((bid & 7) << 3) | (bid >> 5);
  const int tile = (bid >> 3) & 3;
  const int i0   = tile * 512;

  const float* qh = qg + (size_t)head * DDIM * NSEQ;
  const float* kh = kg + (size_t)head * DDIM * NSEQ;
  const float* vh = vg + (size_t)head * DDIM * NSEQ;

  // staging role split: waves 0..7 (t<512) stage K, waves 8..15 stage V
  const int  u   = t & 511;
  const bool isK = (t < 512);
  const int  dp  = u & 31;      // K: d-pair (transpose staging)
  const int  iq  = u >> 5;      // K: j-chunk of 4, 0..15
  const int  vd  = u >> 3;      // V: row (d), 0..63
  const int  sj  = u & 7;       // V: k-slot 0..7
  const int  vg_ = sj >> 2;     // g of slot
  const int  vq  = sj & 3;      // quad of slot

  const float* kp  = kh + (2 * dp) * NSEQ + iq * 4;
  const float* vpA = vh + vd * NSEQ + vg_ * 32 + vq * 4;  // first 4 cols of slot

  // issue tile-0 global loads first: HBM latency hides under Q prestage
  float4v ra, rb;
  if (isK) { ra = *(const float4v*)(kp);  rb = *(const float4v*)(kp + NSEQ); }
  else     { ra = *(const float4v*)(vpA); rb = *(const float4v*)(vpA + 16);  }

  // ---- pre-stage Q: q[d][i0+..] -> Qt[i][d] (512 rows, all 4 buffers) ----
  {
    _Float16* Qt = (_Float16*)smem;
    const float mul = 0.125f * 1.44269504088896340736f;
    const int dpq = t & 31;     // d-pair
    const int ic  = t >> 5;     // i-chunk of 4, 0..31
#pragma unroll
    for (int h = 0; h < 4; ++h) {
      const float* r0 = qh + (2 * dpq) * NSEQ + i0 + h * 128 + ic * 4;
      float4v a = *(const float4v*)(r0);
      float4v b = *(const float4v*)(r0 + NSEQ);
      _Float16* base = Qt + (h * 128 + ic * 4) * STR + 2 * dpq;
#pragma unroll
      for (int s = 0; s < 4; ++s) {
        half2v hh = {(_Float16)(a[s] * mul), (_Float16)(b[s] * mul)};
        *(half2v*)(base + s * STR) = hh;
      }
    }
  }
  __syncthreads();

  // Q B-fragments — live all kernel (2 x 16-col groups per wave)
  const _Float16* Qt = (const _Float16*)smem;
  half8 bq[2][2];
#pragma unroll
  for (int ig = 0; ig < 2; ++ig) {
    bq[ig][0] = *(const half8*)(Qt + (w * 32 + ig * 16 + n16) * STR + quad * 8);
    bq[ig][1] = *(const half8*)(Qt + (w * 32 + ig * 16 + n16) * STR + 32 + quad * 8);
  }
  __syncthreads();  // all Q reads drained before tile 0 overwrites buf1

  const half8 ones = {1.0f16, 1.0f16, 1.0f16, 1.0f16,
                      1.0f16, 1.0f16, 1.0f16, 1.0f16};

  float4v o[2][4];          // [ig][dt]: O^T[d = dt*16+quad*4+r][i-group ig]
  float4v lac[2];           // row-sum accumulators (all regs equal l[n16])
#pragma unroll
  for (int ig = 0; ig < 2; ++ig) {
#pragma unroll
    for (int dt = 0; dt < 4; ++dt) o[ig][dt] = (float4v){0.f, 0.f, 0.f, 0.f};
    lac[ig] = (float4v){0.f, 0.f, 0.f, 0.f};
  }

  // ---- stage tile 0 into buf1 ----
  {
    _Float16* Ktw = (_Float16*)(smem + BUFB);
    if (isK) {
      _Float16* base = Ktw + (iq * 4) * STR + 2 * dp;
#pragma unroll
      for (int s = 0; s < 4; ++s) {
        half2v hh = {(_Float16)ra[s], (_Float16)rb[s]};
        *(half2v*)(base + s * STR) = hh;
      }
    } else {
      // V pre-permuted: slot sj holds orig cols {g*32+vq*4..+3, g*32+16+vq*4..+3}
      half8 hv = {(_Float16)ra[0], (_Float16)ra[1], (_Float16)ra[2], (_Float16)ra[3],
                  (_Float16)rb[0], (_Float16)rb[1], (_Float16)rb[2], (_Float16)rb[3]};
      *(half8*)(Ktw + 64 * STR + vd * STR + sj * 8) = hv;
    }
  }
  __syncthreads();

  for (int kt = 0; kt < 32; ++kt) {
    const _Float16* Kt = (const _Float16*)(smem + ((kt + 1) & 1) * BUFB);
    const _Float16* Vt = Kt + 64 * STR;

    // ---- prefetch next tile into regs (in flight during compute) ----
    if (kt < 31) {
      const int j1 = (kt + 1) * 64;
      if (isK) { ra = *(const float4v*)(kp + j1); rb = *(const float4v*)(kp + NSEQ + j1); }
      else     { ra = *(const float4v*)(vpA + j1); rb = *(const float4v*)(vpA + j1 + 16); }
    }

    // ---- S^T + exp2 per j16 block (K-frags reused across 2 i-groups) ----
    half4v p[2][4];  // [ig][jt]
#pragma unroll
    for (int jt = 0; jt < 4; ++jt) {
      half8 kfa = *(const half8*)(Kt + (jt * 16 + n16) * STR + quad * 8);
      half8 kfb = *(const half8*)(Kt + (jt * 16 + n16) * STR + 32 + quad * 8);
#pragma unroll
      for (int ig = 0; ig < 2; ++ig) {
        float4v sa = {0.f, 0.f, 0.f, 0.f};
        sa = __builtin_amdgcn_mfma_f32_16x16x32_f16(kfa, bq[ig][0], sa, 0, 0, 0);
        sa = __builtin_amdgcn_mfma_f32_16x16x32_f16(kfb, bq[ig][1], sa, 0, 0, 0);
        p[ig][jt] = (half4v){(_Float16)__builtin_amdgcn_exp2f(sa[0]),
                             (_Float16)__builtin_amdgcn_exp2f(sa[1]),
                             (_Float16)__builtin_amdgcn_exp2f(sa[2]),
                             (_Float16)__builtin_amdgcn_exp2f(sa[3])};
      }
    }

    // ---- concat adjacent j16 frags -> K=32 B-operands (k-slot perm) ----
    half8 pg[2][2];
#pragma unroll
    for (int ig = 0; ig < 2; ++ig) {
      pg[ig][0] = __builtin_shufflevector(p[ig][0], p[ig][1], 0, 1, 2, 3, 4, 5, 6, 7);
      pg[ig][1] = __builtin_shufflevector(p[ig][2], p[ig][3], 0, 1, 2, 3, 4, 5, 6, 7);
    }

    // ---- staging moved BEFORE the MFMA cluster: cvt fills the VALU gap,
    //      ds_writes drain under the 20 MFMAs below (T14 write-early) ----
    if (kt < 31) {
      _Float16* Ktw = (_Float16*)(smem + (kt & 1) * BUFB);
      if (isK) {
        _Float16* base = Ktw + (iq * 4) * STR + 2 * dp;
#pragma unroll
        for (int s = 0; s < 4; ++s) {
          half2v hh = {(_Float16)ra[s], (_Float16)rb[s]};
          *(half2v*)(base + s * STR) = hh;
        }
      } else {
        half8 hv = {(_Float16)ra[0], (_Float16)ra[1], (_Float16)ra[2], (_Float16)ra[3],
                    (_Float16)rb[0], (_Float16)rb[1], (_Float16)rb[2], (_Float16)rb[3]};
        *(half8*)(Ktw + 64 * STR + vd * STR + sj * 8) = hv;
      }
    }

    // ---- pure-MFMA cluster: lac row-sums + PV (T5 setprio) ----
    __builtin_amdgcn_s_setprio(1);
#pragma unroll
    for (int ig = 0; ig < 2; ++ig) {
      lac[ig] = __builtin_amdgcn_mfma_f32_16x16x32_f16(ones, pg[ig][0], lac[ig], 0, 0, 0);
      lac[ig] = __builtin_amdgcn_mfma_f32_16x16x32_f16(ones, pg[ig][1], lac[ig], 0, 0, 0);
    }
    // PV at K=32: V A-frag is ONE b128 (pre-permuted k-slot layout),
    // reused across 2 i-groups
#pragma unroll
    for (int dt = 0; dt < 4; ++dt) {
#pragma unroll
      for (int g = 0; g < 2; ++g) {
        half8 vaf = *(const half8*)(Vt + (dt * 16 + n16) * STR + (g * 4 + quad) * 8);
#pragma unroll
        for (int ig = 0; ig < 2; ++ig) {
          o[ig][dt] = __builtin_amdgcn_mfma_f32_16x16x32_f16(
              vaf, pg[ig][g], o[ig][dt], 0, 0, 0);
        }
      }
    }
    __builtin_amdgcn_s_setprio(0);

    if (kt < 31) __syncthreads();
  }

  // ---- epilogue: all regs of lac hold l[i]; direct O^T stores ----
#pragma unroll
  for (int ig = 0; ig < 2; ++ig) {
    const float inv = 1.0f / lac[ig][0];
    float* ob = og + (size_t)head * DDIM * NSEQ + i0 + w * 32 + ig * 16 + n16;
#pragma unroll
    for (int dt = 0; dt < 4; ++dt) {
#pragma unroll
      for (int r = 0; r < 4; ++r) {
        ob[(size_t)(dt * 16 + quad * 4 + r) * NSEQ] = o[ig][dt][r] * inv;
      }
    }
  }
}

extern "C" void kernel_launch(void* const* d_in, const int* in_sizes, int n_in,
                              void* d_out, int out_size, void* d_ws, size_t ws_size,
                              hipStream_t stream) {
  (void)in_sizes; (void)n_in; (void)d_ws; (void)ws_size; (void)out_size;
  const float* q = (const float*)d_in[0];
  const float* k = (const float*)d_in[1];
  const float* v = (const float*)d_in[2];
  attn_fwd<<<dim3(256), dim3(1024), 0, stream>>>(q, k, v, (float*)d_out);
}